// Round 19
// baseline (347.994 us; speedup 1.0000x reference)
//
#include <hip/hip_runtime.h>

// Problem constants (match reference file)
constexpr int D = 128;       // node feature dim
constexpr int R = 64;        // edge feature dim (in = out)
constexpr int CAP = 64;      // per-dst bucket capacity (in-deg ~ Poisson(16))
constexpr int OVF_CAP = 65536;
constexpr int TPAD = 68;     // padded tile row stride (floats)

typedef float floatx4 __attribute__((ext_vector_type(4)));
typedef short bf16x8 __attribute__((ext_vector_type(8)));
typedef float f32x4 __attribute__((ext_vector_type(4)));

static __device__ __forceinline__ float4 f4fma(float a, float4 w, float4 c) {
  c.x = fmaf(a, w.x, c.x); c.y = fmaf(a, w.y, c.y);
  c.z = fmaf(a, w.z, c.z); c.w = fmaf(a, w.w, c.w);
  return c;
}

static __device__ __forceinline__ float selk(float4 a, int kk) {
  return (kk == 0) ? a.x : (kk == 1) ? a.y : (kk == 2) ? a.z : a.w;
}

// ---- bf16 helpers (RNE) ----
static __device__ __forceinline__ unsigned pack_bf16x2(float lo, float hi) {
  unsigned ulo = __float_as_uint(lo), uhi = __float_as_uint(hi);
  ulo += 0x7FFFu + ((ulo >> 16) & 1u);
  uhi += 0x7FFFu + ((uhi >> 16) & 1u);
  return (ulo >> 16) | (uhi & 0xFFFF0000u);
}
static __device__ __forceinline__ short f2bf(float f) {
  unsigned u = __float_as_uint(f);
  u += 0x7FFFu + ((u >> 16) & 1u);
  return (short)(u >> 16);
}
static __device__ __forceinline__ float bf_lo(unsigned u) { return __uint_as_float(u << 16); }
static __device__ __forceinline__ float bf_hi(unsigned u) { return __uint_as_float(u & 0xFFFF0000u); }

__global__ void k_init(int* deg_out, int* cursor, int* ovf_cnt, int n) {
  int i = blockIdx.x * blockDim.x + threadIdx.x;
  if (i < n) { deg_out[i] = 1; cursor[i] = 0; }  // deg_out=1: self loop
  if (i == 0) ovf_cnt[0] = 0;
}

__global__ void k_fill(const int* __restrict__ src, const int* __restrict__ dst,
                       int* deg_out, int* cursor, int* bucket,
                       int* ovf_cnt, int2* ovf, int e) {
  int i = blockIdx.x * blockDim.x + threadIdx.x;
  if (i >= e) return;
  int d = dst[i], s = src[i];
  atomicAdd(&deg_out[s], 1);
  int slot = atomicAdd(&cursor[d], 1);
  if (slot < CAP) bucket[(size_t)d * CAP + slot] = s;
  else {
    int oi = atomicAdd(ovf_cnt, 1);
    if (oi < OVF_CAP) ovf[oi] = make_int2(s, d);
  }
}

// fused: norms (ns, nd) + bf16 pack of x*ns.  One thread = 8 floats.
__global__ __launch_bounds__(256) void k_prep(const float* __restrict__ X,
                                              const int* __restrict__ deg_out,
                                              const int* __restrict__ cursor,
                                              float* __restrict__ ns,
                                              float* __restrict__ nd,
                                              uint4* __restrict__ xs, int n16) {
  int idx = blockIdx.x * 256 + threadIdx.x;
  if (idx >= n16) return;
  int row = idx >> 4, g = idx & 15;
  float s = rsqrtf((float)deg_out[row]);
  if (g == 0) {
    ns[row] = s;
    nd[row] = rsqrtf((float)(cursor[row] + 1));
  }
  const float4* xp = (const float4*)(X + (size_t)row * D + g * 8);
  float4 a = xp[0], b = xp[1];
  uint4 o;
  o.x = pack_bf16x2(a.x * s, a.y * s);
  o.y = pack_bf16x2(a.z * s, a.w * s);
  o.z = pack_bf16x2(b.x * s, b.y * s);
  o.w = pack_bf16x2(b.z * s, b.w * s);
  xs[(size_t)row * 16 + g] = o;
}

// one-time: relW (64x64 f32) -> bf16 MFMA B-fragments, frag-ordered so k_rel
// loads them as 8 fully-coalesced uint4 per thread (index = lane id).
// wf[ct*128 + h*64 + kg*16 + lr] = uint4 of 8 bf16: elem i = W[h*32+kg*8+i][ct*16+lr]
__global__ void k_wprep(const float* __restrict__ Wr, uint4* __restrict__ wf) {
  int t = threadIdx.x;
  for (int q = t; q < 512; q += 256) {
    int lr = q & 15, kg = (q >> 4) & 3, h = (q >> 6) & 1, ct = q >> 7;
    const float* wp = Wr + (size_t)(h * 32 + kg * 8) * 64 + ct * 16 + lr;
    uint4 o;
    o.x = pack_bf16x2(wp[0 * 64], wp[1 * 64]);
    o.y = pack_bf16x2(wp[2 * 64], wp[3 * 64]);
    o.z = pack_bf16x2(wp[4 * 64], wp[5 * 64]);
    o.w = pack_bf16x2(wp[6 * 64], wp[7 * 64]);
    wf[q] = o;
  }
}

// bf16 gather-aggregate (norms pre-folded into XS). 32 lanes/node, uint2/lane.
__global__ __launch_bounds__(256) void k_agg_b(const unsigned* __restrict__ XS,
                                               const int* __restrict__ cursor,
                                               const int* __restrict__ bucket,
                                               float* __restrict__ agg, int n) {
  int g = threadIdx.x >> 5, lane = threadIdx.x & 31;
  int v = blockIdx.x * 8 + g;
  if (v >= n) return;
  float4 acc;
  {
    uint2 u = ((const uint2*)(XS + (size_t)v * 64))[lane];
    acc.x = bf_lo(u.x); acc.y = bf_hi(u.x); acc.z = bf_lo(u.y); acc.w = bf_hi(u.y);
  }
  int cnt = min(cursor[v], CAP);
  const int* bk = bucket + (size_t)v * CAP;
  int i = 0;
  for (; i + 8 <= cnt; i += 8) {
    uint2 u[8];
#pragma unroll
    for (int j = 0; j < 8; ++j)
      u[j] = ((const uint2*)(XS + (size_t)bk[i + j] * 64))[lane];
#pragma unroll
    for (int j = 0; j < 8; ++j) {
      acc.x += bf_lo(u[j].x); acc.y += bf_hi(u[j].x);
      acc.z += bf_lo(u[j].y); acc.w += bf_hi(u[j].y);
    }
  }
  for (; i < cnt; ++i) {
    uint2 u0 = ((const uint2*)(XS + (size_t)bk[i] * 64))[lane];
    acc.x += bf_lo(u0.x); acc.y += bf_hi(u0.x);
    acc.z += bf_lo(u0.y); acc.w += bf_hi(u0.y);
  }
  ((float4*)(agg + (size_t)v * D))[lane] = acc;
}

// Rare overflow edges: f32 atomics from bf16 source, normally zero work.
__global__ __launch_bounds__(128) void k_ovf_b(const unsigned* __restrict__ XS,
                                               const int* __restrict__ ovf_cnt,
                                               const int2* __restrict__ ovf,
                                               float* agg) {
  int m = min(ovf_cnt[0], OVF_CAP);
  int t = threadIdx.x;
  for (int i = blockIdx.x; i < m; i += gridDim.x) {
    int2 e = ovf[i];
    unsigned u = XS[(size_t)e.x * 64 + (t >> 1)];
    float f = (t & 1) ? bf_hi(u) : bf_lo(u);
    atomicAdd(&agg[(size_t)e.y * D + t], f);
  }
}

// z = agg[r] @ W; o = relu(z*nd[r] + b).
// bf16out: store bf16(o * post[r]) to outb (layer 1, post=ns) ; else f32 o to outf.
__global__ __launch_bounds__(256) void k_gemm_relu(const float* __restrict__ A,
                                                   const float* __restrict__ ndv,
                                                   const float* __restrict__ W,
                                                   const float* __restrict__ bias,
                                                   const float* __restrict__ post,
                                                   float* __restrict__ outf,
                                                   unsigned* __restrict__ outb,
                                                   int n) {
  __shared__ float Wl[D * D];  // 64 KiB
  int t = threadIdx.x;
  for (int i = t; i < (D * D) / 4; i += 256) ((float4*)Wl)[i] = ((const float4*)W)[i];
  __syncthreads();

  int ct = t & 15, rg = t >> 4;
  int c0 = ct << 2;
  int row0 = blockIdx.x * 64;

  float4 bb0 = *(const float4*)(bias + c0);
  float4 bb1 = *(const float4*)(bias + c0 + 64);

  int r[4]; const float4* Ap[4];
#pragma unroll
  for (int m = 0; m < 4; ++m) {
    r[m] = row0 + rg + 16 * m;
    int rc = (r[m] < n) ? r[m] : (n - 1);
    Ap[m] = (const float4*)(A + (size_t)rc * D);
  }

  float4 acc[4][2];
#pragma unroll
  for (int m = 0; m < 4; ++m) {
    acc[m][0] = make_float4(0.f, 0.f, 0.f, 0.f);
    acc[m][1] = make_float4(0.f, 0.f, 0.f, 0.f);
  }

#pragma unroll 8
  for (int k4 = 0; k4 < 32; ++k4) {
    float4 a0 = Ap[0][k4], a1 = Ap[1][k4], a2 = Ap[2][k4], a3 = Ap[3][k4];
    const float* wbase = Wl + (k4 << 9) + c0;
#pragma unroll
    for (int kk = 0; kk < 4; ++kk) {
      float4 w0 = *(const float4*)(wbase + (kk << 7));
      float4 w1 = *(const float4*)(wbase + (kk << 7) + 64);
      float e0 = selk(a0, kk), e1 = selk(a1, kk), e2 = selk(a2, kk), e3 = selk(a3, kk);
      acc[0][0] = f4fma(e0, w0, acc[0][0]); acc[0][1] = f4fma(e0, w1, acc[0][1]);
      acc[1][0] = f4fma(e1, w0, acc[1][0]); acc[1][1] = f4fma(e1, w1, acc[1][1]);
      acc[2][0] = f4fma(e2, w0, acc[2][0]); acc[2][1] = f4fma(e2, w1, acc[2][1]);
      acc[3][0] = f4fma(e3, w0, acc[3][0]); acc[3][1] = f4fma(e3, w1, acc[3][1]);
    }
  }

#pragma unroll
  for (int m = 0; m < 4; ++m) {
    if (r[m] < n) {
      float ndr = ndv[r[m]];
      float4 o0, o1;
      o0.x = fmaxf(fmaf(acc[m][0].x, ndr, bb0.x), 0.f);
      o0.y = fmaxf(fmaf(acc[m][0].y, ndr, bb0.y), 0.f);
      o0.z = fmaxf(fmaf(acc[m][0].z, ndr, bb0.z), 0.f);
      o0.w = fmaxf(fmaf(acc[m][0].w, ndr, bb0.w), 0.f);
      o1.x = fmaxf(fmaf(acc[m][1].x, ndr, bb1.x), 0.f);
      o1.y = fmaxf(fmaf(acc[m][1].y, ndr, bb1.y), 0.f);
      o1.z = fmaxf(fmaf(acc[m][1].z, ndr, bb1.z), 0.f);
      o1.w = fmaxf(fmaf(acc[m][1].w, ndr, bb1.w), 0.f);
      if (outb) {
        float ps = post[r[m]];
        uint2 p0, p1;
        p0.x = pack_bf16x2(o0.x * ps, o0.y * ps);
        p0.y = pack_bf16x2(o0.z * ps, o0.w * ps);
        p1.x = pack_bf16x2(o1.x * ps, o1.y * ps);
        p1.y = pack_bf16x2(o1.z * ps, o1.w * ps);
        *(uint2*)(outb + (size_t)r[m] * 64 + (c0 >> 1)) = p0;
        *(uint2*)(outb + (size_t)r[m] * 64 + (c0 >> 1) + 32) = p1;
      } else {
        *(float4*)(outf + (size_t)r[m] * D + c0) = o0;
        *(float4*)(outf + (size_t)r[m] * D + c0 + 64) = o1;
      }
    }
  }
}

// e_h rows [0,E): text_h[row] @ relW + relb ; rows [E,E+N): relb (zero text).
// v11: R16 staging + MFMA, minus per-block W build (precomputed bf16 frags,
// 8 coalesced uint4 loads) and minus LDS transpose (plain cached scalar
// stores; wave's 16 (ct,r) stores fully cover the 128B lines -> L2 merges
// to full-line writebacks, so no nt and no write amplification).
__global__ __launch_bounds__(256) void k_rel_mfma(const float* __restrict__ T,
                                                  const uint4* __restrict__ wf,
                                                  const float* __restrict__ br,
                                                  float* __restrict__ out,
                                                  int e, int ntot) {
  __shared__ float Tl[128 * TPAD];  // 34.8 KiB -> 4 blocks/CU
  int t = threadIdx.x;
  int tile = blockIdx.x;
  const float4 z4 = make_float4(0.f, 0.f, 0.f, 0.f);

  // 1) issue coalesced T-tile loads first (128 rows x 16 float4)
  float4 pre[8];
#pragma unroll
  for (int j = 0; j < 8; ++j) {
    int idx = t + 256 * j, rr = idx >> 4, c4 = idx & 15;
    int grow = tile * 128 + rr;
    pre[j] = (grow < e) ? ((const float4*)T)[(size_t)grow * 16 + c4] : z4;
  }

  // 2) W B-fragments: 8 coalesced uint4 loads (overlap the T loads in flight)
  int l = t & 63;
  int wid = t >> 6;
  int lr = l & 15;        // A-row / B-col / C-col index
  int kg = l >> 4;        // k-group 0..3
  union { uint4 u; bf16x8 v; } cv;
  bf16x8 bfrag[4][2];
#pragma unroll
  for (int ct = 0; ct < 4; ++ct)
#pragma unroll
    for (int h = 0; h < 2; ++h) {
      cv.u = wf[ct * 128 + h * 64 + kg * 16 + lr];
      bfrag[ct][h] = cv.v;
    }
  float bias[4];
#pragma unroll
  for (int ct = 0; ct < 4; ++ct) bias[ct] = br[ct * 16 + lr];

  // 3) regs -> LDS, sync
#pragma unroll
  for (int j = 0; j < 8; ++j) {
    int idx = t + 256 * j, rr = idx >> 4, c4 = idx & 15;
    *(float4*)&Tl[rr * TPAD + (c4 << 2)] = pre[j];
  }
  __syncthreads();

  // 4) MFMA + direct stores: wave wid owns rows wid*32..wid*32+31
#pragma unroll
  for (int g = 0; g < 2; ++g) {
    int lrow = wid * 32 + g * 16 + lr;
    const float* tp = &Tl[lrow * TPAD];
    bf16x8 afrag[2];
#pragma unroll
    for (int h = 0; h < 2; ++h) {
      float4 a0 = *(const float4*)(tp + h * 32 + kg * 8);
      float4 a1 = *(const float4*)(tp + h * 32 + kg * 8 + 4);
      afrag[h][0] = f2bf(a0.x); afrag[h][1] = f2bf(a0.y);
      afrag[h][2] = f2bf(a0.z); afrag[h][3] = f2bf(a0.w);
      afrag[h][4] = f2bf(a1.x); afrag[h][5] = f2bf(a1.y);
      afrag[h][6] = f2bf(a1.z); afrag[h][7] = f2bf(a1.w);
    }
    int R0 = tile * 128 + wid * 32 + g * 16;
#pragma unroll
    for (int ct = 0; ct < 4; ++ct) {
      f32x4 acc;
      acc[0] = bias[ct]; acc[1] = bias[ct]; acc[2] = bias[ct]; acc[3] = bias[ct];
      acc = __builtin_amdgcn_mfma_f32_16x16x32_bf16(afrag[0], bfrag[ct][0], acc, 0, 0, 0);
      acc = __builtin_amdgcn_mfma_f32_16x16x32_bf16(afrag[1], bfrag[ct][1], acc, 0, 0, 0);
#pragma unroll
      for (int r = 0; r < 4; ++r) {
        int orow = R0 + kg * 4 + r;              // C/D row = (lane>>4)*4 + reg
        if (orow < ntot)
          out[(size_t)orow * R + ct * 16 + lr] = acc[r];
      }
    }
  }
}

extern "C" void kernel_launch(void* const* d_in, const int* in_sizes, int n_in,
                              void* d_out, int out_size, void* d_ws, size_t ws_size,
                              hipStream_t stream) {
  const int*   src  = (const int*)d_in[0];
  const int*   dst  = (const int*)d_in[1];
  const float* x    = (const float*)d_in[2];
  const float* text = (const float*)d_in[3];
  const float* W1   = (const float*)d_in[4];
  const float* b1   = (const float*)d_in[5];
  const float* W2   = (const float*)d_in[6];
  const float* b2   = (const float*)d_in[7];
  const float* relW = (const float*)d_in[8];
  const float* relb = (const float*)d_in[9];

  const int E = in_sizes[0];
  const int N = in_sizes[2] / D;

  float* outH = (float*)d_out;
  float* outE = outH + (size_t)N * D;

  // workspace carve-out (256B aligned)
  char* w = (char*)d_ws;
  auto alloc = [&](size_t bytes) -> void* {
    void* p = (void*)w;
    w += (bytes + 255) & ~(size_t)255;
    return p;
  };
  int*      deg_out  = (int*)alloc((size_t)N * 4);
  int*      cursor   = (int*)alloc((size_t)N * 4);
  float*    norm_src = (float*)alloc((size_t)N * 4);
  float*    norm_dst = (float*)alloc((size_t)N * 4);
  int*      ovf_cnt  = (int*)alloc(256);
  int2*     ovf      = (int2*)alloc((size_t)OVF_CAP * 8);
  int*      bucket   = (int*)alloc((size_t)N * CAP * 4);
  float*    agg      = (float*)alloc((size_t)N * D * 4);
  unsigned* xs       = (unsigned*)alloc((size_t)N * 64 * 4);   // bf16 x*ns
  unsigned* h1p      = (unsigned*)alloc((size_t)N * 64 * 4);   // bf16 h1*ns
  uint4*    wfrag    = (uint4*)alloc(8192);                    // bf16 relW frags

  int nbN = (N + 255) / 256;
  int nbE = (E + 255) / 256;

  k_init<<<nbN, 256, 0, stream>>>(deg_out, cursor, ovf_cnt, N);
  k_wprep<<<1, 256, 0, stream>>>(relW, wfrag);
  k_fill<<<nbE, 256, 0, stream>>>(src, dst, deg_out, cursor, bucket, ovf_cnt, ovf, E);
  k_prep<<<(N * 16 + 255) / 256, 256, 0, stream>>>(x, deg_out, cursor,
                                                   norm_src, norm_dst, (uint4*)xs, N * 16);

  // layer 1: agg1 = gather(xs); h1p = bf16(relu((agg1@W1)*nd+b1)*ns)
  k_agg_b<<<(N + 7) / 8, 256, 0, stream>>>(xs, cursor, bucket, agg, N);
  k_ovf_b<<<64, 128, 0, stream>>>(xs, ovf_cnt, ovf, agg);
  k_gemm_relu<<<(N + 63) / 64, 256, 0, stream>>>(agg, norm_dst, W1, b1, norm_src,
                                                 nullptr, h1p, N);

  // layer 2: agg2 = gather(h1p); h2 = relu((agg2@W2)*nd+b2) -> outH (f32)
  k_agg_b<<<(N + 7) / 8, 256, 0, stream>>>(h1p, cursor, bucket, agg, N);
  k_ovf_b<<<64, 128, 0, stream>>>(h1p, ovf_cnt, ovf, agg);
  k_gemm_relu<<<(N + 63) / 64, 256, 0, stream>>>(agg, norm_dst, W2, b2, nullptr,
                                                 outH, nullptr, N);

  // edge features (MFMA + precomputed W frags + direct cached stores)
  int ntot = E + N;
  int nBlk = (ntot + 127) / 128;
  k_rel_mfma<<<nBlk, 256, 0, stream>>>(text, wfrag, relb, outE, E, ntot);
}

// Round 20
// 335.683 us; speedup vs baseline: 1.0367x; 1.0367x over previous
//
#include <hip/hip_runtime.h>

// Problem constants (match reference file)
constexpr int D = 128;       // node feature dim
constexpr int R = 64;        // edge feature dim (in = out)
constexpr int CAP = 64;      // per-dst bucket capacity (in-deg ~ Poisson(16))
constexpr int OVF_CAP = 65536;
constexpr int TPAD = 68;     // padded T-tile row stride (16B-aligned rows, bank-spread)

typedef float floatx4 __attribute__((ext_vector_type(4)));  // native vec for nontemporal builtins
typedef short bf16x8 __attribute__((ext_vector_type(8)));   // MFMA A/B fragment (8 bf16)
typedef float f32x4 __attribute__((ext_vector_type(4)));    // MFMA C/D fragment

static __device__ __forceinline__ float4 f4fma(float a, float4 w, float4 c) {
  c.x = fmaf(a, w.x, c.x); c.y = fmaf(a, w.y, c.y);
  c.z = fmaf(a, w.z, c.z); c.w = fmaf(a, w.w, c.w);
  return c;
}

static __device__ __forceinline__ void nt_store4(float4 v, float* p) {
  floatx4 q; q.x = v.x; q.y = v.y; q.z = v.z; q.w = v.w;
  __builtin_nontemporal_store(q, (floatx4*)p);
}

static __device__ __forceinline__ float selk(float4 a, int kk) {
  return (kk == 0) ? a.x : (kk == 1) ? a.y : (kk == 2) ? a.z : a.w;
}

// ---- bf16 helpers (RNE) ----
static __device__ __forceinline__ unsigned pack_bf16x2(float lo, float hi) {
  unsigned ulo = __float_as_uint(lo), uhi = __float_as_uint(hi);
  ulo += 0x7FFFu + ((ulo >> 16) & 1u);
  uhi += 0x7FFFu + ((uhi >> 16) & 1u);
  return (ulo >> 16) | (uhi & 0xFFFF0000u);
}
static __device__ __forceinline__ short f2bf(float f) {
  unsigned u = __float_as_uint(f);
  u += 0x7FFFu + ((u >> 16) & 1u);
  return (short)(u >> 16);
}
static __device__ __forceinline__ float bf_lo(unsigned u) { return __uint_as_float(u << 16); }
static __device__ __forceinline__ float bf_hi(unsigned u) { return __uint_as_float(u & 0xFFFF0000u); }

__global__ void k_init(int* deg_out, int* cursor, int* ovf_cnt, int n) {
  int i = blockIdx.x * blockDim.x + threadIdx.x;
  if (i < n) { deg_out[i] = 1; cursor[i] = 0; }  // deg_out=1: self loop
  if (i == 0) ovf_cnt[0] = 0;
}

// merged degree-count + bucket-fill: deg_in recovered as cursor+1 afterwards
__global__ void k_fill(const int* __restrict__ src, const int* __restrict__ dst,
                       int* deg_out, int* cursor, int* bucket,
                       int* ovf_cnt, int2* ovf, int e) {
  int i = blockIdx.x * blockDim.x + threadIdx.x;
  if (i >= e) return;
  int d = dst[i], s = src[i];
  atomicAdd(&deg_out[s], 1);
  int slot = atomicAdd(&cursor[d], 1);
  if (slot < CAP) bucket[(size_t)d * CAP + slot] = s;
  else {
    int oi = atomicAdd(ovf_cnt, 1);
    if (oi < OVF_CAP) ovf[oi] = make_int2(s, d);
  }
}

__global__ void k_norm(const int* __restrict__ deg_out, const int* __restrict__ cursor,
                       float* ns, float* nd, int n) {
  int i = blockIdx.x * blockDim.x + threadIdx.x;
  if (i < n) {
    ns[i] = rsqrtf((float)deg_out[i]);
    nd[i] = rsqrtf((float)(cursor[i] + 1));   // +1 = self loop
  }
}

// xs[v][d] = bf16( x[v][d] * ns[v] ).  One thread = 8 floats -> uint4.
__global__ __launch_bounds__(256) void k_prep(const float* __restrict__ X,
                                              const float* __restrict__ ns,
                                              uint4* __restrict__ xs, int n16) {
  int idx = blockIdx.x * 256 + threadIdx.x;
  if (idx >= n16) return;
  int row = idx >> 4, g = idx & 15;
  const float4* xp = (const float4*)(X + (size_t)row * D + g * 8);
  float4 a = xp[0], b = xp[1];
  float s = ns[row];
  uint4 o;
  o.x = pack_bf16x2(a.x * s, a.y * s);
  o.y = pack_bf16x2(a.z * s, a.w * s);
  o.z = pack_bf16x2(b.x * s, b.y * s);
  o.w = pack_bf16x2(b.z * s, b.w * s);
  xs[(size_t)row * 16 + g] = o;
}

// bf16 gather-aggregate (norms pre-folded into XS).
// agg[v] = XS[v] + sum_{(s->v)} XS[s], f32 accum. 32 lanes/node, uint2/lane.
__global__ __launch_bounds__(256) void k_agg_b(const unsigned* __restrict__ XS,
                                               const int* __restrict__ cursor,
                                               const int* __restrict__ bucket,
                                               float* __restrict__ agg, int n) {
  int g = threadIdx.x >> 5, lane = threadIdx.x & 31;
  int v = blockIdx.x * 8 + g;
  if (v >= n) return;
  float4 acc;
  {
    uint2 u = ((const uint2*)(XS + (size_t)v * 64))[lane];
    acc.x = bf_lo(u.x); acc.y = bf_hi(u.x); acc.z = bf_lo(u.y); acc.w = bf_hi(u.y);
  }
  int cnt = min(cursor[v], CAP);
  const int* bk = bucket + (size_t)v * CAP;
  int i = 0;
  for (; i + 4 <= cnt; i += 4) {
    int s0 = bk[i], s1 = bk[i + 1], s2 = bk[i + 2], s3 = bk[i + 3];
    uint2 u0 = ((const uint2*)(XS + (size_t)s0 * 64))[lane];
    uint2 u1 = ((const uint2*)(XS + (size_t)s1 * 64))[lane];
    uint2 u2 = ((const uint2*)(XS + (size_t)s2 * 64))[lane];
    uint2 u3 = ((const uint2*)(XS + (size_t)s3 * 64))[lane];
    acc.x += bf_lo(u0.x) + bf_lo(u1.x) + bf_lo(u2.x) + bf_lo(u3.x);
    acc.y += bf_hi(u0.x) + bf_hi(u1.x) + bf_hi(u2.x) + bf_hi(u3.x);
    acc.z += bf_lo(u0.y) + bf_lo(u1.y) + bf_lo(u2.y) + bf_lo(u3.y);
    acc.w += bf_hi(u0.y) + bf_hi(u1.y) + bf_hi(u2.y) + bf_hi(u3.y);
  }
  for (; i < cnt; ++i) {
    int s0 = bk[i];
    uint2 u0 = ((const uint2*)(XS + (size_t)s0 * 64))[lane];
    acc.x += bf_lo(u0.x); acc.y += bf_hi(u0.x);
    acc.z += bf_lo(u0.y); acc.w += bf_hi(u0.y);
  }
  ((float4*)(agg + (size_t)v * D))[lane] = acc;
}

// Rare overflow edges (slot >= CAP): f32 atomics from bf16 source, normally zero work.
__global__ __launch_bounds__(128) void k_ovf_b(const unsigned* __restrict__ XS,
                                               const int* __restrict__ ovf_cnt,
                                               const int2* __restrict__ ovf,
                                               float* agg) {
  int m = min(ovf_cnt[0], OVF_CAP);
  int t = threadIdx.x;
  for (int i = blockIdx.x; i < m; i += gridDim.x) {
    int2 e = ovf[i];
    unsigned u = XS[(size_t)e.x * 64 + (t >> 1)];
    float f = (t & 1) ? bf_hi(u) : bf_lo(u);
    atomicAdd(&agg[(size_t)e.y * D + t], f);
  }
}

// z = agg[r] @ W; o = relu(z*nd[r] + b).
// bf16out: store bf16(o * post[r]) to outb (layer 1, post=ns) ; else f32 o to outf.
__global__ __launch_bounds__(256) void k_gemm_relu(const float* __restrict__ A,
                                                   const float* __restrict__ ndv,
                                                   const float* __restrict__ W,
                                                   const float* __restrict__ bias,
                                                   const float* __restrict__ post,
                                                   float* __restrict__ outf,
                                                   unsigned* __restrict__ outb,
                                                   int n) {
  __shared__ float Wl[D * D];  // 64 KiB
  int t = threadIdx.x;
  for (int i = t; i < (D * D) / 4; i += 256) ((float4*)Wl)[i] = ((const float4*)W)[i];
  __syncthreads();

  int ct = t & 15, rg = t >> 4;
  int c0 = ct << 2;            // cols c0..c0+3 and c0+64..c0+67
  int row0 = blockIdx.x * 64;

  float4 bb0 = *(const float4*)(bias + c0);
  float4 bb1 = *(const float4*)(bias + c0 + 64);

  int r[4]; const float4* Ap[4];
#pragma unroll
  for (int m = 0; m < 4; ++m) {
    r[m] = row0 + rg + 16 * m;
    int rc = (r[m] < n) ? r[m] : (n - 1);
    Ap[m] = (const float4*)(A + (size_t)rc * D);
  }

  float4 acc[4][2];
#pragma unroll
  for (int m = 0; m < 4; ++m) {
    acc[m][0] = make_float4(0.f, 0.f, 0.f, 0.f);
    acc[m][1] = make_float4(0.f, 0.f, 0.f, 0.f);
  }

#pragma unroll 8
  for (int k4 = 0; k4 < 32; ++k4) {
    float4 a0 = Ap[0][k4], a1 = Ap[1][k4], a2 = Ap[2][k4], a3 = Ap[3][k4];
    const float* wbase = Wl + (k4 << 9) + c0;
#pragma unroll
    for (int kk = 0; kk < 4; ++kk) {
      float4 w0 = *(const float4*)(wbase + (kk << 7));
      float4 w1 = *(const float4*)(wbase + (kk << 7) + 64);
      float e0 = selk(a0, kk), e1 = selk(a1, kk), e2 = selk(a2, kk), e3 = selk(a3, kk);
      acc[0][0] = f4fma(e0, w0, acc[0][0]); acc[0][1] = f4fma(e0, w1, acc[0][1]);
      acc[1][0] = f4fma(e1, w0, acc[1][0]); acc[1][1] = f4fma(e1, w1, acc[1][1]);
      acc[2][0] = f4fma(e2, w0, acc[2][0]); acc[2][1] = f4fma(e2, w1, acc[2][1]);
      acc[3][0] = f4fma(e3, w0, acc[3][0]); acc[3][1] = f4fma(e3, w1, acc[3][1]);
    }
  }

#pragma unroll
  for (int m = 0; m < 4; ++m) {
    if (r[m] < n) {
      float ndr = ndv[r[m]];
      float4 o0, o1;
      o0.x = fmaxf(fmaf(acc[m][0].x, ndr, bb0.x), 0.f);
      o0.y = fmaxf(fmaf(acc[m][0].y, ndr, bb0.y), 0.f);
      o0.z = fmaxf(fmaf(acc[m][0].z, ndr, bb0.z), 0.f);
      o0.w = fmaxf(fmaf(acc[m][0].w, ndr, bb0.w), 0.f);
      o1.x = fmaxf(fmaf(acc[m][1].x, ndr, bb1.x), 0.f);
      o1.y = fmaxf(fmaf(acc[m][1].y, ndr, bb1.y), 0.f);
      o1.z = fmaxf(fmaf(acc[m][1].z, ndr, bb1.z), 0.f);
      o1.w = fmaxf(fmaf(acc[m][1].w, ndr, bb1.w), 0.f);
      if (outb) {
        float ps = post[r[m]];
        uint2 p0, p1;
        p0.x = pack_bf16x2(o0.x * ps, o0.y * ps);
        p0.y = pack_bf16x2(o0.z * ps, o0.w * ps);
        p1.x = pack_bf16x2(o1.x * ps, o1.y * ps);
        p1.y = pack_bf16x2(o1.z * ps, o1.w * ps);
        *(uint2*)(outb + (size_t)r[m] * 64 + (c0 >> 1)) = p0;
        *(uint2*)(outb + (size_t)r[m] * 64 + (c0 >> 1) + 32) = p1;
      } else {
        *(float4*)(outf + (size_t)r[m] * D + c0) = o0;
        *(float4*)(outf + (size_t)r[m] * D + c0 + 64) = o1;
      }
    }
  }
}

// e_h rows [0,E): text_h[row] @ relW + relb ; rows [E,E+N): relb (zero text).
// v10 (R16-proven 336.7us total): coalesced global->LDS staging + MFMA
// (verified frags) + LDS transpose epilogue + coalesced nt float4 stores.
__global__ __launch_bounds__(256) void k_rel_mfma(const float* __restrict__ T,
                                                  const float* __restrict__ Wr,
                                                  const float* __restrict__ br,
                                                  float* __restrict__ out,
                                                  int e, int ntot) {
  __shared__ float Tl[128 * TPAD];  // 34.8 KiB -> 4 blocks/CU
  int t = threadIdx.x;
  int tile = blockIdx.x;
  const float4 z4 = make_float4(0.f, 0.f, 0.f, 0.f);

  // 1) issue coalesced T-tile loads first (128 rows x 16 float4)
  float4 pre[8];
#pragma unroll
  for (int j = 0; j < 8; ++j) {
    int idx = t + 256 * j, rr = idx >> 4, c4 = idx & 15;
    int grow = tile * 128 + rr;
    pre[j] = (grow < e) ? ((const float4*)T)[(size_t)grow * 16 + c4] : z4;
  }

  // 2) W B-fragments build overlaps the loads in flight
  int l = t & 63;
  int wid = t >> 6;
  int lr = l & 15;        // A-row / B-col / C-col index
  int kg = l >> 4;        // k-group 0..3
  bf16x8 bfrag[4][2];
#pragma unroll
  for (int ct = 0; ct < 4; ++ct)
#pragma unroll
    for (int h = 0; h < 2; ++h) {
      const float* wp = Wr + (size_t)(h * 32 + kg * 8) * 64 + ct * 16 + lr;
#pragma unroll
      for (int i = 0; i < 8; ++i) bfrag[ct][h][i] = f2bf(wp[(size_t)i * 64]);
    }
  float bias[4];
#pragma unroll
  for (int ct = 0; ct < 4; ++ct) bias[ct] = br[ct * 16 + lr];

  // 3) regs -> LDS, sync
#pragma unroll
  for (int j = 0; j < 8; ++j) {
    int idx = t + 256 * j, rr = idx >> 4, c4 = idx & 15;
    *(float4*)&Tl[rr * TPAD + (c4 << 2)] = pre[j];
  }
  __syncthreads();

  // 4) MFMA: wave wid owns rows wid*32..wid*32+31 (2 groups of 16); keep all acc live
  f32x4 acc2[2][4];
#pragma unroll
  for (int g = 0; g < 2; ++g) {
    int lrow = wid * 32 + g * 16 + lr;          // local tile row
    const float* tp = &Tl[lrow * TPAD];
    bf16x8 afrag[2];
#pragma unroll
    for (int h = 0; h < 2; ++h) {
      float4 a0 = *(const float4*)(tp + h * 32 + kg * 8);      // k = h*32+kg*8 ..+3
      float4 a1 = *(const float4*)(tp + h * 32 + kg * 8 + 4);  // k = ..+4..+7
      afrag[h][0] = f2bf(a0.x); afrag[h][1] = f2bf(a0.y);
      afrag[h][2] = f2bf(a0.z); afrag[h][3] = f2bf(a0.w);
      afrag[h][4] = f2bf(a1.x); afrag[h][5] = f2bf(a1.y);
      afrag[h][6] = f2bf(a1.z); afrag[h][7] = f2bf(a1.w);
    }
#pragma unroll
    for (int ct = 0; ct < 4; ++ct) {
      f32x4 acc;
      acc[0] = bias[ct]; acc[1] = bias[ct]; acc[2] = bias[ct]; acc[3] = bias[ct];
      acc = __builtin_amdgcn_mfma_f32_16x16x32_bf16(afrag[0], bfrag[ct][0], acc, 0, 0, 0);
      acc = __builtin_amdgcn_mfma_f32_16x16x32_bf16(afrag[1], bfrag[ct][1], acc, 0, 0, 0);
      acc2[g][ct] = acc;
    }
  }

  // 5) transpose through LDS: scatter acc (C/D layout) -> row-major Tl
  __syncthreads();   // all waves done reading A-frags from Tl
#pragma unroll
  for (int g = 0; g < 2; ++g)
#pragma unroll
    for (int ct = 0; ct < 4; ++ct)
#pragma unroll
      for (int r = 0; r < 4; ++r)
        Tl[(wid * 32 + g * 16 + kg * 4 + r) * TPAD + ct * 16 + lr] = acc2[g][ct][r];
  __syncthreads();

  // 6) coalesced nt stores: wave-instr = 4 rows x 256B contiguous
#pragma unroll
  for (int j = 0; j < 8; ++j) {
    int idx = t + 256 * j, rr = idx >> 4, c4 = idx & 15;
    int grow = tile * 128 + rr;
    if (grow < ntot)
      nt_store4(*(float4*)&Tl[rr * TPAD + (c4 << 2)], out + (size_t)grow * R + (c4 << 2));
  }
}

extern "C" void kernel_launch(void* const* d_in, const int* in_sizes, int n_in,
                              void* d_out, int out_size, void* d_ws, size_t ws_size,
                              hipStream_t stream) {
  const int*   src  = (const int*)d_in[0];
  const int*   dst  = (const int*)d_in[1];
  const float* x    = (const float*)d_in[2];
  const float* text = (const float*)d_in[3];
  const float* W1   = (const float*)d_in[4];
  const float* b1   = (const float*)d_in[5];
  const float* W2   = (const float*)d_in[6];
  const float* b2   = (const float*)d_in[7];
  const float* relW = (const float*)d_in[8];
  const float* relb = (const float*)d_in[9];

  const int E = in_sizes[0];
  const int N = in_sizes[2] / D;

  float* outH = (float*)d_out;
  float* outE = outH + (size_t)N * D;

  // workspace carve-out (256B aligned)
  char* w = (char*)d_ws;
  auto alloc = [&](size_t bytes) -> void* {
    void* p = (void*)w;
    w += (bytes + 255) & ~(size_t)255;
    return p;
  };
  int*      deg_out  = (int*)alloc((size_t)N * 4);
  int*      cursor   = (int*)alloc((size_t)N * 4);
  float*    norm_src = (float*)alloc((size_t)N * 4);
  float*    norm_dst = (float*)alloc((size_t)N * 4);
  int*      ovf_cnt  = (int*)alloc(256);
  int2*     ovf      = (int2*)alloc((size_t)OVF_CAP * 8);
  int*      bucket   = (int*)alloc((size_t)N * CAP * 4);
  float*    agg      = (float*)alloc((size_t)N * D * 4);
  unsigned* xs       = (unsigned*)alloc((size_t)N * 64 * 4);   // bf16 x*ns
  unsigned* h1p      = (unsigned*)alloc((size_t)N * 64 * 4);   // bf16 h1*ns

  int nbN = (N + 255) / 256;
  int nbE = (E + 255) / 256;

  k_init<<<nbN, 256, 0, stream>>>(deg_out, cursor, ovf_cnt, N);
  k_fill<<<nbE, 256, 0, stream>>>(src, dst, deg_out, cursor, bucket, ovf_cnt, ovf, E);
  k_norm<<<nbN, 256, 0, stream>>>(deg_out, cursor, norm_src, norm_dst, N);

  // layer 1: xs = bf16(x*ns); agg1 = gather(xs); h1p = bf16(relu((agg1@W1)*nd+b1)*ns)
  k_prep<<<(N * 16 + 255) / 256, 256, 0, stream>>>(x, norm_src, (uint4*)xs, N * 16);
  k_agg_b<<<(N + 7) / 8, 256, 0, stream>>>(xs, cursor, bucket, agg, N);
  k_ovf_b<<<64, 128, 0, stream>>>(xs, ovf_cnt, ovf, agg);
  k_gemm_relu<<<(N + 63) / 64, 256, 0, stream>>>(agg, norm_dst, W1, b1, norm_src,
                                                 nullptr, h1p, N);

  // layer 2: agg2 = gather(h1p); h2 = relu((agg2@W2)*nd+b2) -> outH (f32)
  k_agg_b<<<(N + 7) / 8, 256, 0, stream>>>(h1p, cursor, bucket, agg, N);
  k_ovf_b<<<64, 128, 0, stream>>>(h1p, ovf_cnt, ovf, agg);
  k_gemm_relu<<<(N + 63) / 64, 256, 0, stream>>>(agg, norm_dst, W2, b2, nullptr,
                                                 outH, nullptr, N);

  // edge features (MFMA + LDS-staged T + transpose epilogue)
  int ntot = E + N;
  int nBlk = (ntot + 127) / 128;
  k_rel_mfma<<<nBlk, 256, 0, stream>>>(text, relW, relb, outE, E, ntot);
}